// Round 2
// baseline (1172.269 us; speedup 1.0000x reference)
//
#include <hip/hip_runtime.h>

#define D 256
#define K 128
#define BM 64
#define DC 32

// ---------------- kernel 0: copy centroids to out (f32) + compute c2[k] ----------------
__global__ void prep_kernel(const float* __restrict__ C,
                            float* __restrict__ out_ce,
                            float* __restrict__ c2) {
    int k = blockIdx.x;
    int d = threadIdx.x;           // 0..255
    float v = C[k * D + d];
    out_ce[k * D + d] = v;         // output dtype is f32: exact copy
    float sq = v * v;
    // wave reduce (64 lanes)
    for (int off = 32; off > 0; off >>= 1) sq += __shfl_down(sq, off, 64);
    __shared__ float s[4];
    int lane = d & 63, w = d >> 6;
    if (lane == 0) s[w] = sq;
    __syncthreads();
    if (d == 0) c2[k] = s[0] + s[1] + s[2] + s[3];
}

// ---------------- kernel 1: tiled fp32 GEMM + gumbel-argmax one-hot ----------------
__global__ __launch_bounds__(256) void assign_kernel(
    const float* __restrict__ seq, const float* __restrict__ u,
    const float* __restrict__ C, const float* __restrict__ c2g,
    float* __restrict__ out, int N)
{
    __shared__ float As[DC][68];    // [d][row], padded
    __shared__ float Bs[DC][132];   // [d][k]

    const int tid = threadIdx.x;
    const int tx = tid & 15;        // k-group: ks [tx*8, tx*8+8)
    const int ty = tid >> 4;        // row-group: rows [ty*4, ty*4+4)
    const int rowBase = blockIdx.x * BM;

    float acc[4][8];
    float x2[4];
#pragma unroll
    for (int i = 0; i < 4; i++) {
        x2[i] = 0.f;
#pragma unroll
        for (int j = 0; j < 8; j++) acc[i][j] = 0.f;
    }

    for (int dc = 0; dc < D; dc += DC) {
        // stage A: 64 rows x 32 cols (transposed into LDS)
#pragma unroll
        for (int t = 0; t < 2; t++) {
            int s  = tid + t * 256;
            int r  = s >> 3;
            int c4 = (s & 7) * 4;
            int n  = rowBase + r;
            float4 v = make_float4(0.f, 0.f, 0.f, 0.f);
            if (n < N) v = *(const float4*)(seq + (size_t)n * D + dc + c4);
            As[c4 + 0][r] = v.x; As[c4 + 1][r] = v.y;
            As[c4 + 2][r] = v.z; As[c4 + 3][r] = v.w;
        }
        // stage B: 128 k x 32 cols (transposed into LDS)
#pragma unroll
        for (int t = 0; t < 4; t++) {
            int s  = tid + t * 256;
            int k  = s >> 3;
            int c4 = (s & 7) * 4;
            float4 v = *(const float4*)(C + k * D + dc + c4);
            Bs[c4 + 0][k] = v.x; Bs[c4 + 1][k] = v.y;
            Bs[c4 + 2][k] = v.z; Bs[c4 + 3][k] = v.w;
        }
        __syncthreads();
#pragma unroll
        for (int d = 0; d < DC; d++) {
            float4 a  = *(const float4*)&As[d][ty * 4];
            float4 b0 = *(const float4*)&Bs[d][tx * 8];
            float4 b1 = *(const float4*)&Bs[d][tx * 8 + 4];
            float av[4] = {a.x, a.y, a.z, a.w};
            float bv[8] = {b0.x, b0.y, b0.z, b0.w, b1.x, b1.y, b1.z, b1.w};
#pragma unroll
            for (int i = 0; i < 4; i++) {
                x2[i] = fmaf(av[i], av[i], x2[i]);
#pragma unroll
                for (int j = 0; j < 8; j++)
                    acc[i][j] = fmaf(av[i], bv[j], acc[i][j]);
            }
        }
        __syncthreads();
    }

    // epilogue: score = sqrt(max(x2 - 2*dot + c2, 0)); logit = score + gumbel; argmax -> one-hot
    float c2v[8];
#pragma unroll
    for (int j = 0; j < 8; j++) c2v[j] = c2g[tx * 8 + j];

    const float EPS = 1e-10f;
#pragma unroll
    for (int i = 0; i < 4; i++) {
        int n = rowBase + ty * 4 + i;   // uniform across the 16-lane tx group
        float uu[8] = {0.5f, 0.5f, 0.5f, 0.5f, 0.5f, 0.5f, 0.5f, 0.5f};
        if (n < N) {
            float4 u0 = *(const float4*)(u + (size_t)n * K + tx * 8);
            float4 u1 = *(const float4*)(u + (size_t)n * K + tx * 8 + 4);
            uu[0] = u0.x; uu[1] = u0.y; uu[2] = u0.z; uu[3] = u0.w;
            uu[4] = u1.x; uu[5] = u1.y; uu[6] = u1.z; uu[7] = u1.w;
        }
        float bestV = -1e30f;
        int   bestK = 0;
#pragma unroll
        for (int j = 0; j < 8; j++) {
            // match np op order: (x2 - 2*dot) + c2 ; 2*dot is exact (pow2 scale)
            float t = x2[i] - 2.0f * acc[i][j];
            t += c2v[j];
            float score = sqrtf(fmaxf(t, 0.f));
            float g = -logf(-logf(uu[j] + EPS) + EPS);
            float logit = score + g;     // tau = 1.0
            if (logit > bestV) { bestV = logit; bestK = tx * 8 + j; }  // first index wins ties
        }
        // butterfly across the 16 tx-lanes (same ty => same row)
#pragma unroll
        for (int off = 1; off < 16; off <<= 1) {
            float ov = __shfl_xor(bestV, off, 64);
            int   ok = __shfl_xor(bestK, off, 64);
            if (ov > bestV || (ov == bestV && ok < bestK)) { bestV = ov; bestK = ok; }
        }
        if (n < N) {
            float w[8];
#pragma unroll
            for (int j = 0; j < 8; j++)
                w[j] = ((tx * 8 + j) == bestK) ? 1.0f : 0.0f;
            float* p = out + (size_t)n * K + tx * 8;
            *(float4*)(p)     = make_float4(w[0], w[1], w[2], w[3]);
            *(float4*)(p + 4) = make_float4(w[4], w[5], w[6], w[7]);
        }
    }
}

extern "C" void kernel_launch(void* const* d_in, const int* in_sizes, int n_in,
                              void* d_out, int out_size, void* d_ws, size_t ws_size,
                              hipStream_t stream) {
    const float* seq = (const float*)d_in[0];   // [N, 256] f32
    const float* u   = (const float*)d_in[1];   // [N, 128] f32
    const float* C   = (const float*)d_in[2];   // [128, 256] f32
    float* out = (float*)d_out;                 // f32 outputs (reference dtype)

    int N = in_sizes[0] / D;                    // 500000
    float* c2 = (float*)d_ws;                   // K floats

    // output 0: community_embed (f32 copy), plus c2 precompute
    prep_kernel<<<K, D, 0, stream>>>(C, out, c2);

    // output 1: assignmat (one-hot), offset K*D floats
    float* out_assign = out + (size_t)K * D;
    int grid = (N + BM - 1) / BM;
    assign_kernel<<<grid, 256, 0, stream>>>(seq, u, C, c2, out_assign, N);
}